// Round 17
// baseline (229.600 us; speedup 1.0000x reference)
//
#include <hip/hip_runtime.h>
#include <math.h>

namespace {

constexpr int T   = 4096;
constexpr int C   = 512;
constexpr int NB  = 8;
constexpr int NS  = 512;
constexpr int HD  = 64;
constexpr int KA  = 8;
constexpr int EA  = 24;
constexpr int EF  = 16;
constexpr int KF  = 2;
constexpr int HID = 1024;

typedef __attribute__((ext_vector_type(8))) short bf16x8;
typedef __attribute__((ext_vector_type(4))) float f32x4;

__device__ inline unsigned short f2bf(float f) {
  unsigned u = __float_as_uint(f);
  return (unsigned short)((u + 0x7FFFu + ((u >> 16) & 1u)) >> 16);
}
__device__ inline float bf2f(unsigned short u) {
  return __uint_as_float((unsigned)u << 16);
}

template <int E, int TS>
__device__ inline bool tile_from_counts(const int* counts, int tile, int& e_out, int& t0_out) {
  int e = 0;
  for (; e < E; e++) {
    int nt = (counts[e] + TS - 1) / TS;
    if (tile < nt) break;
    tile -= nt;
  }
  e_out = e; t0_out = tile * TS;
  return e < E;
}

// ---- Fused [residual+]LN + gating + bucket-scatter + loss-stats: 16 tokens, 1024 thr ----
template <int E, int K, bool RESID>
__global__ __launch_bounds__(1024) void ln_gate_kernel(
    const float* __restrict__ in, const unsigned short* __restrict__ yslot,
    float* __restrict__ resid_out,
    const float* __restrict__ g, const float* __restrict__ b,
    const float* __restrict__ gate_all, const int* __restrict__ task,
    unsigned short* __restrict__ outb, float* __restrict__ gates,
    int* __restrict__ counts, int* __restrict__ bucket, int stride,
    float* __restrict__ psum_g, float* __restrict__ zsum_g) {
  constexpr int TPB = 16;
  constexpr int XSS = 516;
  int tid = threadIdx.x, lane = tid & 63, wv = tid >> 6;   // 16 waves
  int tb = blockIdx.x * TPB;
  __shared__ float xs[TPB][XSS];
  __shared__ float lp[2][TPB][E];
  __shared__ __align__(16) float Wt[E][XSS];
  __shared__ int idx_s[TPB][8];
  __shared__ float zbuf[TPB];
  __shared__ int lcount[E];
  __shared__ int lbase[E];
  const float* W = gate_all + (size_t)task[0] * C * E;
  for (int i = tid; i < C * E; i += 1024) {
    int c = i / E, e = i - c * E;
    Wt[e][c] = W[i];
  }
  if (tid < E) lcount[tid] = 0;
  int c0 = lane * 8;
  const float4 g0 = *(const float4*)&g[c0], g1 = *(const float4*)&g[c0 + 4];
  const float4 b0 = *(const float4*)&b[c0], b1 = *(const float4*)&b[c0 + 4];
  {
    int tt = wv;
    int t = tb + tt;
    const float* row = in + (size_t)t * C + c0;
    float4 v0 = *(const float4*)&row[0];
    float4 v1 = *(const float4*)&row[4];
    if (RESID) {
      #pragma unroll
      for (int k = 0; k < KA; k++) {
        uint4 u = *(const uint4*)&yslot[((size_t)t * KA + k) * C + c0];
        const unsigned short* us = (const unsigned short*)&u;
        v0.x += bf2f(us[0]); v0.y += bf2f(us[1]); v0.z += bf2f(us[2]); v0.w += bf2f(us[3]);
        v1.x += bf2f(us[4]); v1.y += bf2f(us[5]); v1.z += bf2f(us[6]); v1.w += bf2f(us[7]);
      }
      *(float4*)&resid_out[(size_t)t * C + c0]     = v0;
      *(float4*)&resid_out[(size_t)t * C + c0 + 4] = v1;
    }
    float s = (v0.x + v0.y) + (v0.z + v0.w) + (v1.x + v1.y) + (v1.z + v1.w);
    #pragma unroll
    for (int m = 1; m < 64; m <<= 1) s += __shfl_xor(s, m);
    float mean = s * (1.f / C);
    float d[8] = {v0.x - mean, v0.y - mean, v0.z - mean, v0.w - mean,
                  v1.x - mean, v1.y - mean, v1.z - mean, v1.w - mean};
    float vv = 0.f;
    #pragma unroll
    for (int j = 0; j < 8; j++) vv += d[j] * d[j];
    #pragma unroll
    for (int m = 1; m < 64; m <<= 1) vv += __shfl_xor(vv, m);
    float r = rsqrtf(vv * (1.f / C) + 1e-5f);
    float o[8];
    o[0] = d[0] * r * g0.x + b0.x; o[1] = d[1] * r * g0.y + b0.y;
    o[2] = d[2] * r * g0.z + b0.z; o[3] = d[3] * r * g0.w + b0.w;
    o[4] = d[4] * r * g1.x + b1.x; o[5] = d[5] * r * g1.y + b1.y;
    o[6] = d[6] * r * g1.z + b1.z; o[7] = d[7] * r * g1.w + b1.w;
    *(ushort4*)&outb[(size_t)t * C + c0] =
        make_ushort4(f2bf(o[0]), f2bf(o[1]), f2bf(o[2]), f2bf(o[3]));
    *(ushort4*)&outb[(size_t)t * C + c0 + 4] =
        make_ushort4(f2bf(o[4]), f2bf(o[5]), f2bf(o[6]), f2bf(o[7]));
    #pragma unroll
    for (int j = 0; j < 8; j++) xs[tt][c0 + j] = o[j];
  }
  __syncthreads();
  if (tid < TPB * E * 2) {
    int half = tid / (TPB * E);
    int rem = tid - half * (TPB * E);
    int e = rem % E, tt = rem / E;
    int cb = half * (C / 2);
    float a0 = 0.f, a1 = 0.f, a2 = 0.f, a3 = 0.f;
    float a4 = 0.f, a5 = 0.f, a6 = 0.f, a7 = 0.f;
    #pragma unroll 4
    for (int c = cb; c < cb + C / 2; c += 8) {
      const float4 xv0 = *(const float4*)&xs[tt][c];
      const float4 xv1 = *(const float4*)&xs[tt][c + 4];
      const float4 wv0 = *(const float4*)&Wt[e][c];
      const float4 wv1 = *(const float4*)&Wt[e][c + 4];
      a0 += xv0.x * wv0.x; a1 += xv0.y * wv0.y;
      a2 += xv0.z * wv0.z; a3 += xv0.w * wv0.w;
      a4 += xv1.x * wv1.x; a5 += xv1.y * wv1.y;
      a6 += xv1.z * wv1.z; a7 += xv1.w * wv1.w;
    }
    lp[half][tt][e] = ((a0 + a1) + (a2 + a3)) + ((a4 + a5) + (a6 + a7));
  }
  __syncthreads();
  {
    int tt = wv;
    int t = tb + tt;
    float lgv = (lane < E) ? (lp[0][tt][lane] + lp[1][tt][lane]) : -3.0e38f;
    float mx = lgv;
    #pragma unroll
    for (int m = 1; m < 64; m <<= 1) mx = fmaxf(mx, __shfl_xor(mx, m));
    float pe = (lane < E) ? expf(lgv - mx) : 0.f;
    float sum = pe;
    #pragma unroll
    for (int m = 1; m < 64; m <<= 1) sum += __shfl_xor(sum, m);
    float inv = 1.f / sum;
    float prob = pe * inv;
    if (lane < E) lp[0][tt][lane] = prob;
    if (lane == 0) zbuf[tt] = mx + logf(sum);
    float pv = (lane < E) ? prob : -1.f;
    float gsum = 0.f, myv = 0.f; int myi = 0;
    for (int k = 0; k < K; k++) {
      float bv = pv; int bi_ = lane;
      #pragma unroll
      for (int m = 1; m < 64; m <<= 1) {
        float ov = __shfl_xor(bv, m); int oi = __shfl_xor(bi_, m);
        if (ov > bv || (ov == bv && oi < bi_)) { bv = ov; bi_ = oi; }
      }
      gsum += bv;
      if (lane == k) { myv = bv; myi = bi_; }
      if (lane == bi_) pv = -1.f;
    }
    if (lane < K) {
      float ginv = 1.f / (gsum + 1e-6f);
      gates[(size_t)t * K + lane] = myv * ginv;
      idx_s[tt][lane] = myi;
    }
  }
  __syncthreads();
  if (tid < E) {
    float s = 0.f;
    #pragma unroll
    for (int tt2 = 0; tt2 < TPB; tt2++) s += lp[0][tt2][tid];
    atomicAdd(&psum_g[tid], s);
  }
  if (tid == 64) {
    float z = 0.f;
    #pragma unroll
    for (int tt2 = 0; tt2 < TPB; tt2++) { float l = zbuf[tt2]; z += l * l; }
    atomicAdd(zsum_g, z);
  }
  int my_e = -1, my_lpos = 0;
  if (tid < TPB * K) {
    int tt2 = tid / K, k = tid % K;
    my_e = idx_s[tt2][k];
    my_lpos = atomicAdd(&lcount[my_e], 1);
  }
  __syncthreads();
  if (tid < E) lbase[tid] = lcount[tid] ? atomicAdd(&counts[tid], lcount[tid]) : 0;
  __syncthreads();
  if (my_e >= 0) {
    int tt2 = tid / K, k = tid % K;
    bucket[(size_t)my_e * stride + lbase[my_e] + my_lpos] = (tb + tt2) * K + k;
  }
}

// ---------------- merged transpose+cvt: 64x64 tiles, all 5 weight tensors ----------------
__global__ __launch_bounds__(256) void tcvt_all(
    const float* __restrict__ wq, const float* __restrict__ wo_a,
    const float* __restrict__ wi, const float* __restrict__ wo_m,
    const float* __restrict__ kvw,
    unsigned short* __restrict__ wqt, unsigned short* __restrict__ woat,
    unsigned short* __restrict__ wit, unsigned short* __restrict__ womt,
    unsigned short* __restrict__ kvwt) {
  int bid = blockIdx.x;
  const float* src; unsigned short* dst; int K, N, nx, rem;
  if (bid < 192)       { src = wq;   dst = wqt;  K = 512;  N = 64;   nx = 1;  rem = bid; }
  else if (bid < 384)  { src = wo_a; dst = woat; K = 64;   N = 512;  nx = 8;  rem = bid - 192; }
  else if (bid < 2432) { src = wi;   dst = wit;  K = 512;  N = 1024; nx = 16; rem = bid - 384; }
  else if (bid < 4480) { src = wo_m; dst = womt; K = 1024; N = 512;  nx = 8;  rem = bid - 2432; }
  else                 { src = kvw;  dst = kvwt; K = 512;  N = 128;  nx = 2;  rem = bid - 4480; }
  int per = nx * (K / 64);
  int e = rem / per, r2 = rem % per;
  int kt = (r2 / nx) * 64, nt = (r2 % nx) * 64;
  __shared__ float tile[64][65];
  int tid = threadIdx.x;
  const float* S = src + (size_t)e * K * N;
  for (int i = tid; i < 64 * 16; i += 256) {
    int r = i >> 4, c4 = (i & 15) * 4;
    const float4 v = *(const float4*)&S[(size_t)(kt + r) * N + nt + c4];
    tile[r][c4 + 0] = v.x; tile[r][c4 + 1] = v.y;
    tile[r][c4 + 2] = v.z; tile[r][c4 + 3] = v.w;
  }
  __syncthreads();
  unsigned short* D = dst + (size_t)e * K * N;
  for (int i = tid; i < 64 * 64; i += 256) {
    int k = i & 63, n = i >> 6;
    D[(size_t)(nt + n) * K + kt + k] = f2bf(tile[k][n]);
  }
}

// ---------------- Merged Q GEMM + KV GEMM ----------------
__global__ __launch_bounds__(256) void qkv_mfma(
    const unsigned short* __restrict__ xb, const unsigned short* __restrict__ wqt,
    const unsigned short* __restrict__ kvwt, const float* __restrict__ kvb,
    const int* __restrict__ bucket, const int* __restrict__ counts,
    unsigned short* __restrict__ qb, unsigned short* __restrict__ Kb,
    unsigned short* __restrict__ Vt) {
  __shared__ __align__(16) unsigned short smem[16 * 72 + 128 * 72];
  __shared__ int slots[64];
  __shared__ int se, st0;
  int tid = threadIdx.x;
  int lane = tid & 63, w = tid >> 6;
  int lr = lane & 15, lk = (lane >> 4) * 8, rowq = (lane >> 4) * 4;
  if ((int)blockIdx.y < T / 16) {
    int t0 = blockIdx.y * 16;
    unsigned short* Xs = smem;
    unsigned short* Ws = smem + 16 * 72;
    f32x4 acc[2] = {};
    for (int kc = 0; kc < C; kc += 64) {
      __syncthreads();
      if (tid < 128) {
        int r = tid >> 3, c8 = (tid & 7) * 8;
        *(uint4*)&Xs[r * 72 + c8] = *(const uint4*)&xb[(size_t)(t0 + r) * C + kc + c8];
      }
      #pragma unroll
      for (int it = 0; it < 4; ++it) {
        int i = it * 256 + tid;
        int r = i >> 3, c8 = (i & 7) * 8;
        *(uint4*)&Ws[r * 72 + c8] = *(const uint4*)&kvwt[(size_t)r * C + kc + c8];
      }
      __syncthreads();
      #pragma unroll
      for (int kk = 0; kk < 64; kk += 32) {
        bf16x8 xf = *(const bf16x8*)&Xs[lr * 72 + kk + lk];
        #pragma unroll
        for (int cf = 0; cf < 2; cf++) {
          bf16x8 wf = *(const bf16x8*)&Ws[(w * 32 + cf * 16 + lr) * 72 + kk + lk];
          acc[cf] = __builtin_amdgcn_mfma_f32_16x16x32_bf16(wf, xf, acc[cf], 0, 0, 0);
        }
      }
    }
    int t = t0 + lr;
    int bb = t >> 9, n = t & (NS - 1);
    #pragma unroll
    for (int cf = 0; cf < 2; cf++) {
      #pragma unroll
      for (int r2 = 0; r2 < 4; r2++) {
        int c = w * 32 + cf * 16 + rowq + r2;
        float v = acc[cf][r2] + kvb[c];
        if (c < HD) Kb[(size_t)t * HD + c] = f2bf(v);
        else        Vt[((size_t)bb * HD + (c - HD)) * NS + n] = f2bf(v);
      }
    }
  } else {
    if (tid == 0) {
      int e, t0;
      bool ok = tile_from_counts<EA, 64>(counts, blockIdx.y - T / 16, e, t0);
      se = ok ? e : -1; st0 = t0;
    }
    __syncthreads();
    if (se < 0) return;
    int e = se, t0 = st0;
    int cnt = counts[e];
    unsigned short* Xb = smem;
    unsigned short* Wb = smem + 64 * 72;
    if (tid < 64) {
      int ii = t0 + tid;
      slots[tid] = (ii < cnt) ? bucket[(size_t)e * (T * KA) + ii] : -1;
    }
    __syncthreads();
    f32x4 acc[4] = {};
    for (int kc = 0; kc < C; kc += 64) {
      __syncthreads();
      #pragma unroll
      for (int it = 0; it < 2; ++it) {
        int i = it * 256 + tid;
        int r = i >> 3, c8 = (i & 7) * 8;
        int s = slots[r];
        uint4 v = make_uint4(0u, 0u, 0u, 0u);
        if (s >= 0) v = *(const uint4*)&xb[(size_t)(s >> 3) * C + kc + c8];
        *(uint4*)&Xb[r * 72 + c8] = v;
      }
      #pragma unroll
      for (int it = 0; it < 2; ++it) {
        int i = it * 256 + tid;
        int r = i >> 3, c8 = (i & 7) * 8;
        *(uint4*)&Wb[r * 72 + c8] = *(const uint4*)&wqt[((size_t)e * HD + r) * C + kc + c8];
      }
      __syncthreads();
      #pragma unroll
      for (int kk = 0; kk < 64; kk += 32) {
        bf16x8 a = *(const bf16x8*)&Wb[(w * 16 + lr) * 72 + kk + lk];
        #pragma unroll
        for (int mf = 0; mf < 4; mf++) {
          bf16x8 b = *(const bf16x8*)&Xb[(mf * 16 + lr) * 72 + kk + lk];
          acc[mf] = __builtin_amdgcn_mfma_f32_16x16x32_bf16(a, b, acc[mf], 0, 0, 0);
        }
      }
    }
    #pragma unroll
    for (int mf = 0; mf < 4; mf++) {
      int s = slots[mf * 16 + lr];
      if (s < 0) continue;
      ushort4 v = make_ushort4(f2bf(0.125f * acc[mf][0]), f2bf(0.125f * acc[mf][1]),
                               f2bf(0.125f * acc[mf][2]), f2bf(0.125f * acc[mf][3]));
      *(ushort4*)&qb[(size_t)s * HD + w * 16 + rowq] = v;
    }
  }
}

// ---------------- MFMA flash attention: 32-row q-tiles, 128 threads, reg-pipelined K/V ----------------
__global__ __launch_bounds__(128) void attn_mfma(
    const unsigned short* __restrict__ qb, const unsigned short* __restrict__ Kb,
    const unsigned short* __restrict__ Vt, unsigned short* __restrict__ ob) {
  int qt = blockIdx.x, h = blockIdx.y, b = blockIdx.z;
  int tid = threadIdx.x;
  __shared__ __align__(16) unsigned short Qs[32][72];
  __shared__ __align__(16) unsigned short Ks[64][72];
  __shared__ __align__(16) unsigned short Vs[64][72];
  __shared__ __align__(16) unsigned short Ps[32][72];
  int i0 = qt * 32;
  #pragma unroll
  for (int it = 0; it < 2; ++it) {
    int i = it * 128 + tid;
    int r = i >> 3, c8 = (i & 7) * 8;
    *(uint4*)&Qs[r][c8] = *(const uint4*)&qb[(((size_t)(b * NS + i0 + r)) * KA + h) * HD + c8];
  }
  int lane = tid & 63, w = tid >> 6;
  int lr = lane & 15, lk = (lane >> 4) * 8, rowq = (lane >> 4) * 4;
  f32x4 acc_o[4] = {};
  float m_run = -3.0e38f, l_run = 0.f;
  uint4 kr[4], vr[4];
  // prologue: load tile 0 into registers
  #pragma unroll
  for (int it = 0; it < 4; ++it) {
    int i = it * 128 + tid;
    int r = i >> 3, c8 = (i & 7) * 8;
    kr[it] = *(const uint4*)&Kb[((size_t)(b * NS + r)) * HD + c8];
    vr[it] = *(const uint4*)&Vt[((size_t)b * HD + r) * NS + c8];
  }
  for (int jt = 0; jt < NS / 64; ++jt) {
    __syncthreads();   // prior PV done reading LDS; Q staged (first iter)
    #pragma unroll
    for (int it = 0; it < 4; ++it) {
      int i = it * 128 + tid;
      int r = i >> 3, c8 = (i & 7) * 8;
      *(uint4*)&Ks[r][c8] = kr[it];
      *(uint4*)&Vs[r][c8] = vr[it];
    }
    __syncthreads();
    // prefetch next tile into registers; latency hides under compute below
    if (jt + 1 < NS / 64) {
      #pragma unroll
      for (int it = 0; it < 4; ++it) {
        int i = it * 128 + tid;
        int r = i >> 3, c8 = (i & 7) * 8;
        kr[it] = *(const uint4*)&Kb[((size_t)(b * NS + (jt + 1) * 64 + r)) * HD + c8];
        vr[it] = *(const uint4*)&Vt[((size_t)b * HD + r) * NS + (jt + 1) * 64 + c8];
      }
    }
    f32x4 acc_s[4] = {};
    #pragma unroll
    for (int kk = 0; kk < 64; kk += 32) {
      bf16x8 qf = *(const bf16x8*)&Qs[w * 16 + lr][kk + lk];
      #pragma unroll
      for (int kf = 0; kf < 4; kf++) {
        bf16x8 krf = *(const bf16x8*)&Ks[kf * 16 + lr][kk + lk];
        acc_s[kf] = __builtin_amdgcn_mfma_f32_16x16x32_bf16(krf, qf, acc_s[kf], 0, 0, 0);
      }
    }
    float pmax = acc_s[0][0];
    #pragma unroll
    for (int kf = 0; kf < 4; kf++)
      #pragma unroll
      for (int r = 0; r < 4; r++) pmax = fmaxf(pmax, acc_s[kf][r]);
    pmax = fmaxf(pmax, __shfl_xor(pmax, 16));
    pmax = fmaxf(pmax, __shfl_xor(pmax, 32));
    float m_new = fmaxf(m_run, pmax);
    float scl = expf(m_run - m_new);
    float rs = 0.f;
    #pragma unroll
    for (int kf = 0; kf < 4; kf++)
      #pragma unroll
      for (int r = 0; r < 4; r++) {
        float pv = expf(acc_s[kf][r] - m_new);
        rs += pv;
        Ps[w * 16 + lr][kf * 16 + rowq + r] = f2bf(pv);
      }
    rs += __shfl_xor(rs, 16);
    rs += __shfl_xor(rs, 32);
    l_run = l_run * scl + rs;
    m_run = m_new;
    __syncthreads();
    #pragma unroll
    for (int df = 0; df < 4; df++) {
      acc_o[df][0] *= scl; acc_o[df][1] *= scl;
      acc_o[df][2] *= scl; acc_o[df][3] *= scl;
    }
    #pragma unroll
    for (int kk = 0; kk < 64; kk += 32) {
      bf16x8 pf = *(const bf16x8*)&Ps[w * 16 + lr][kk + lk];
      #pragma unroll
      for (int df = 0; df < 4; df++) {
        bf16x8 vf = *(const bf16x8*)&Vs[df * 16 + lr][kk + lk];
        acc_o[df] = __builtin_amdgcn_mfma_f32_16x16x32_bf16(vf, pf, acc_o[df], 0, 0, 0);
      }
    }
  }
  float inv = 1.f / l_run;
  int token = b * NS + i0 + w * 16 + lr;
  #pragma unroll
  for (int df = 0; df < 4; df++) {
    ushort4 v = make_ushort4(f2bf(acc_o[df][0] * inv), f2bf(acc_o[df][1] * inv),
                             f2bf(acc_o[df][2] * inv), f2bf(acc_o[df][3] * inv));
    *(ushort4*)&ob[((size_t)token * KA + h) * HD + df * 16 + rowq] = v;
  }
}

// ---------------- MFMA output proj: 128 slots x 128 cols, K=64 ----------------
__global__ __launch_bounds__(256) void oproj_mfma(
    const unsigned short* __restrict__ ob, const unsigned short* __restrict__ wot,
    const float* __restrict__ gates, const int* __restrict__ bucket,
    const int* __restrict__ counts, unsigned short* __restrict__ y_slot) {
  __shared__ int se, st0;
  int tid = threadIdx.x;
  if (tid == 0) {
    int e, t0;
    bool ok = tile_from_counts<EA, 128>(counts, blockIdx.y, e, t0);
    se = ok ? e : -1; st0 = t0;
  }
  __syncthreads();
  if (se < 0) return;
  int e = se, t0 = st0;
  int c0 = blockIdx.x * 128;
  int cnt = counts[e];
  __shared__ int slots[128];
  __shared__ float gs[128];
  __shared__ __align__(16) unsigned short Xb[128][72];
  __shared__ __align__(16) unsigned short Wb[128][72];
  if (tid < 128) {
    int ii = t0 + tid;
    int s = (ii < cnt) ? bucket[(size_t)e * (T * KA) + ii] : -1;
    slots[tid] = s;
    gs[tid] = (s >= 0) ? gates[s] : 0.f;
  }
  __syncthreads();
  #pragma unroll
  for (int it = 0; it < 4; ++it) {
    int i = it * 256 + tid;
    int r = i >> 3, c8 = (i & 7) * 8;
    int s = slots[r];
    uint4 vo = make_uint4(0u, 0u, 0u, 0u);
    if (s >= 0) {
      float g = gs[r];
      uint4 u = *(const uint4*)&ob[(size_t)s * HD + c8];
      const unsigned short* us = (const unsigned short*)&u;
      unsigned short* vs = (unsigned short*)&vo;
      #pragma unroll
      for (int k = 0; k < 8; k++) vs[k] = f2bf(g * bf2f(us[k]));
    }
    *(uint4*)&Xb[r][c8] = vo;
  }
  #pragma unroll
  for (int it = 0; it < 4; ++it) {
    int i = it * 256 + tid;
    int r = i >> 3, c8 = (i & 7) * 8;
    *(uint4*)&Wb[r][c8] = *(const uint4*)&wot[((size_t)e * C + c0 + r) * HD + c8];
  }
  __syncthreads();
  int lane = tid & 63, wid = tid >> 6;
  int wr = wid & 1, wc = wid >> 1;
  int lr = lane & 15, lk = (lane >> 4) * 8, rowq = (lane >> 4) * 4;
  f32x4 acc[4][4] = {};
  #pragma unroll
  for (int kk = 0; kk < 64; kk += 32) {
    bf16x8 a[4], b[4];
    #pragma unroll
    for (int nf = 0; nf < 4; nf++) a[nf] = *(const bf16x8*)&Wb[wc * 64 + nf * 16 + lr][kk + lk];
    #pragma unroll
    for (int mf = 0; mf < 4; mf++) b[mf] = *(const bf16x8*)&Xb[wr * 64 + mf * 16 + lr][kk + lk];
    #pragma unroll
    for (int nf = 0; nf < 4; nf++)
      #pragma unroll
      for (int mf = 0; mf < 4; mf++)
        acc[nf][mf] = __builtin_amdgcn_mfma_f32_16x16x32_bf16(a[nf], b[mf], acc[nf][mf], 0, 0, 0);
  }
  #pragma unroll
  for (int mf = 0; mf < 4; mf++) {
    int si = wr * 64 + mf * 16 + lr;
    int s = slots[si];
    if (s < 0) continue;
    size_t base = (size_t)s * C + c0 + wc * 64;
    #pragma unroll
    for (int nf = 0; nf < 4; nf++) {
      ushort4 v = make_ushort4(f2bf(acc[nf][mf][0]), f2bf(acc[nf][mf][1]),
                               f2bf(acc[nf][mf][2]), f2bf(acc[nf][mf][3]));
      *(ushort4*)&y_slot[base + nf * 16 + rowq] = v;
    }
  }
}

// ---------------- MFMA MLP1: 64 slots x 64 cols, gelu epilogue ----------------
__global__ __launch_bounds__(256) void mlp1_mfma(
    const unsigned short* __restrict__ xb, const unsigned short* __restrict__ wit,
    const float* __restrict__ bi, const int* __restrict__ bucket,
    const int* __restrict__ counts, unsigned short* __restrict__ h) {
  __shared__ int se, st0;
  int tid = threadIdx.x;
  if (tid == 0) {
    int e, t0;
    bool ok = tile_from_counts<EF, 64>(counts, blockIdx.y, e, t0);
    se = ok ? e : -1; st0 = t0;
  }
  __syncthreads();
  if (se < 0) return;
  int e = se, t0 = st0;
  int j0 = blockIdx.x * 64;
  int cnt = counts[e];
  __shared__ int slots[64];
  __shared__ __align__(16) unsigned short Xb[64][72];
  __shared__ __align__(16) unsigned short Wb[64][72];
  if (tid < 64) {
    int ii = t0 + tid;
    slots[tid] = (ii < cnt) ? bucket[(size_t)e * (T * KF) + ii] : -1;
  }
  __syncthreads();
  int lane = tid & 63, w = tid >> 6;
  int lr = lane & 15, lk = (lane >> 4) * 8, rowq = (lane >> 4) * 4;
  f32x4 acc[4] = {};
  for (int kc = 0; kc < C; kc += 64) {
    __syncthreads();
    #pragma unroll
    for (int it = 0; it < 2; ++it) {
      int i = it * 256 + tid;
      int r = i >> 3, c8 = (i & 7) * 8;
      int s = slots[r];
      uint4 v = make_uint4(0u, 0u, 0u, 0u);
      if (s >= 0) v = *(const uint4*)&xb[(size_t)(s >> 1) * C + kc + c8];
      *(uint4*)&Xb[r][c8] = v;
    }
    #pragma unroll
    for (int it = 0; it < 2; ++it) {
      int i = it * 256 + tid;
      int r = i >> 3, c8 = (i & 7) * 8;
      *(uint4*)&Wb[r][c8] = *(const uint4*)&wit[((size_t)e * HID + j0 + r) * C + kc + c8];
    }
    __syncthreads();
    #pragma unroll
    for (int kk = 0; kk < 64; kk += 32) {
      bf16x8 a = *(const bf16x8*)&Wb[w * 16 + lr][kk + lk];
      #pragma unroll
      for (int mf = 0; mf < 4; mf++) {
        bf16x8 b = *(const bf16x8*)&Xb[mf * 16 + lr][kk + lk];
        acc[mf] = __builtin_amdgcn_mfma_f32_16x16x32_bf16(a, b, acc[mf], 0, 0, 0);
      }
    }
  }
  #pragma unroll
  for (int mf = 0; mf < 4; mf++) {
    int s = slots[mf * 16 + lr];
    if (s < 0) continue;
    int j = j0 + w * 16 + rowq;
    const float4 b4 = *(const float4*)&bi[(size_t)e * HID + j];
    float v0 = acc[mf][0] + b4.x, v1 = acc[mf][1] + b4.y;
    float v2 = acc[mf][2] + b4.z, v3 = acc[mf][3] + b4.w;
    v0 = 0.5f * v0 * (1.f + erff(v0 * 0.70710678118654752f));
    v1 = 0.5f * v1 * (1.f + erff(v1 * 0.70710678118654752f));
    v2 = 0.5f * v2 * (1.f + erff(v2 * 0.70710678118654752f));
    v3 = 0.5f * v3 * (1.f + erff(v3 * 0.70710678118654752f));
    *(ushort4*)&h[(size_t)s * HID + j] = make_ushort4(f2bf(v0), f2bf(v1), f2bf(v2), f2bf(v3));
  }
}

// ---------------- MFMA MLP2: 64 slots x 64 cols, gate+bias epilogue ----------------
__global__ __launch_bounds__(256) void mlp2_mfma(
    const unsigned short* __restrict__ h, const unsigned short* __restrict__ wot,
    const float* __restrict__ bo, const float* __restrict__ gates2,
    const int* __restrict__ bucket, const int* __restrict__ counts,
    unsigned short* __restrict__ y2) {
  __shared__ int se, st0;
  int tid = threadIdx.x;
  if (tid == 0) {
    int e, t0;
    bool ok = tile_from_counts<EF, 64>(counts, blockIdx.y, e, t0);
    se = ok ? e : -1; st0 = t0;
  }
  __syncthreads();
  if (se < 0) return;
  int e = se, t0 = st0;
  int c0 = blockIdx.x * 64;
  int cnt = counts[e];
  __shared__ int slots[64];
  __shared__ __align__(16) unsigned short Xb[64][72];
  __shared__ __align__(16) unsigned short Wb[64][72];
  if (tid < 64) {
    int ii = t0 + tid;
    slots[tid] = (ii < cnt) ? bucket[(size_t)e * (T * KF) + ii] : -1;
  }
  __syncthreads();
  int lane = tid & 63, w = tid >> 6;
  int lr = lane & 15, lk = (lane >> 4) * 8, rowq = (lane >> 4) * 4;
  f32x4 acc[4] = {};
  for (int kc = 0; kc < HID; kc += 64) {
    __syncthreads();
    #pragma unroll
    for (int it = 0; it < 2; ++it) {
      int i = it * 256 + tid;
      int r = i >> 3, c8 = (i & 7) * 8;
      int s = slots[r];
      uint4 v = make_uint4(0u, 0u, 0u, 0u);
      if (s >= 0) v = *(const uint4*)&h[(size_t)s * HID + kc + c8];
      *(uint4*)&Xb[r][c8] = v;
    }
    #pragma unroll
    for (int it = 0; it < 2; ++it) {
      int i = it * 256 + tid;
      int r = i >> 3, c8 = (i & 7) * 8;
      *(uint4*)&Wb[r][c8] = *(const uint4*)&wot[((size_t)e * C + c0 + r) * HID + kc + c8];
    }
    __syncthreads();
    #pragma unroll
    for (int kk = 0; kk < 64; kk += 32) {
      bf16x8 a = *(const bf16x8*)&Wb[w * 16 + lr][kk + lk];
      #pragma unroll
      for (int mf = 0; mf < 4; mf++) {
        bf16x8 b = *(const bf16x8*)&Xb[mf * 16 + lr][kk + lk];
        acc[mf] = __builtin_amdgcn_mfma_f32_16x16x32_bf16(a, b, acc[mf], 0, 0, 0);
      }
    }
  }
  #pragma unroll
  for (int mf = 0; mf < 4; mf++) {
    int s = slots[mf * 16 + lr];
    if (s < 0) continue;
    float g = gates2[s];
    int cc = c0 + w * 16 + rowq;
    const float4 b4 = *(const float4*)&bo[(size_t)e * C + cc];
    ushort4 v = make_ushort4(f2bf(g * (acc[mf][0] + b4.x)),
                             f2bf(g * (acc[mf][1] + b4.y)),
                             f2bf(g * (acc[mf][2] + b4.z)),
                             f2bf(g * (acc[mf][3] + b4.w)));
    *(ushort4*)&y2[(size_t)s * C + cc] = v;
  }
}

// ---------------- Final residual add (bf16 slots) + scalar loss (block 0) ----------------
__global__ void final_kernel(const unsigned short* __restrict__ y2, float* __restrict__ xout,
                             const float* __restrict__ acc, const int* __restrict__ ca,
                             const int* __restrict__ cf, float* __restrict__ loss_out) {
  int t = blockIdx.x, tid = threadIdx.x;
  int c = tid * 2;
  unsigned u0 = *(const unsigned*)&y2[(size_t)(t * 2) * C + c];
  unsigned u1 = *(const unsigned*)&y2[(size_t)(t * 2 + 1) * C + c];
  xout[(size_t)t * C + c]     += bf2f((unsigned short)(u0 & 0xFFFF)) + bf2f((unsigned short)(u1 & 0xFFFF));
  xout[(size_t)t * C + c + 1] += bf2f((unsigned short)(u0 >> 16)) + bf2f((unsigned short)(u1 >> 16));
  if (t == 0 && tid == 0) {
    const float* p1 = acc;      float z1 = acc[48];
    const float* p2 = acc + 49; float z2 = acc[81];
    float sp1 = 0.f, sf1 = 0.f;
    for (int e = 0; e < 24; e++) { sp1 += p1[e]; sf1 += (float)ca[e]; }
    float sw1 = 0.f;
    for (int e = 0; e < 24; e++) sw1 += (p1[e] / sp1) * ((float)ca[e] / sf1);
    sw1 *= 24.f;
    float sp2 = 0.f, sf2 = 0.f;
    for (int e = 0; e < 16; e++) { sp2 += p2[e]; sf2 += (float)cf[e]; }
    float sw2 = 0.f;
    for (int e = 0; e < 16; e++) sw2 += (p2[e] / sp2) * ((float)cf[e] / sf2);
    sw2 *= 16.f;
    loss_out[0] = 0.01f * sw1 + 0.001f * (z1 / T) + 0.01f * sw2 + 0.001f * (z2 / T);
  }
}

}  // namespace

extern "C" void kernel_launch(void* const* d_in, const int* in_sizes, int n_in,
                              void* d_out, int out_size, void* d_ws, size_t ws_size,
                              hipStream_t stream) {
  const float* x      = (const float*)d_in[0];
  const int*   task   = (const int*)d_in[1];
  const float* n1g    = (const float*)d_in[2];
  const float* n1b    = (const float*)d_in[3];
  const float* gate_a = (const float*)d_in[4];
  const float* wq     = (const float*)d_in[5];
  const float* wo_a   = (const float*)d_in[6];
  const float* kvw    = (const float*)d_in[7];
  const float* kvb    = (const float*)d_in[8];
  const float* n2g    = (const float*)d_in[9];
  const float* n2b    = (const float*)d_in[10];
  const float* gate_m = (const float*)d_in[11];
  const float* wi     = (const float*)d_in[12];
  const float* bi     = (const float*)d_in[13];
  const float* wo_m   = (const float*)d_in[14];
  const float* bo     = (const float*)d_in[15];
  float* out = (float*)d_out;

  char* p = (char*)d_ws;
  unsigned short* x1b = (unsigned short*)p; p += (size_t)T * C * 2;
  unsigned short* qb = (unsigned short*)p;  p += (size_t)T * KA * HD * 2;
  unsigned short* ob = (unsigned short*)p;  p += (size_t)T * KA * HD * 2;
  unsigned short* Kb = (unsigned short*)p;  p += (size_t)T * HD * 2;
  unsigned short* Vt = (unsigned short*)p;  p += (size_t)T * HD * 2;
  char* un = p;                      p += (size_t)T * KA * C * 2;
  unsigned short* y_slot  = (unsigned short*)un;
  unsigned short* h       = (unsigned short*)un;
  unsigned short* y2_slot = (unsigned short*)(un + (size_t)T * KF * HID * 2);
  unsigned short* wqt = (unsigned short*)p;  p += (size_t)EA * C * HD * 2;
  unsigned short* woat = (unsigned short*)p; p += (size_t)EA * HD * C * 2;
  unsigned short* wit = (unsigned short*)p;  p += (size_t)EF * C * HID * 2;
  unsigned short* womt = (unsigned short*)p; p += (size_t)EF * HID * C * 2;
  unsigned short* kvwt = (unsigned short*)p; p += (size_t)(2 * HD) * C * 2;
  float* gates1 = (float*)p;         p += (size_t)T * KA * 4;
  float* gates2 = (float*)p;         p += (size_t)T * KF * 4;
  int* bucket_a = (int*)p;           p += (size_t)EA * (T * KA) * 4;
  int* bucket_f = (int*)p;           p += (size_t)EF * (T * KF) * 4;
  int* counts_a = (int*)p;           p += 32 * 4;
  int* counts_f = (int*)p;           p += 32 * 4;
  float* accum = (float*)p;          p += 128 * 4;

  hipMemsetAsync(counts_a, 0, (32 + 32 + 128) * 4, stream);

  tcvt_all<<<4496, 256, 0, stream>>>(wq, wo_a, wi, wo_m, kvw, wqt, woat, wit, womt, kvwt);

  ln_gate_kernel<EA, KA, false><<<T / 16, 1024, 0, stream>>>(
      x, y_slot, out, n1g, n1b, gate_a, task, x1b, gates1,
      counts_a, bucket_a, T * KA, accum, accum + 48);
  qkv_mfma<<<dim3(1, T / 16 + 536), 256, 0, stream>>>(x1b, wqt, kvwt, kvb,
                                                      bucket_a, counts_a, qb, Kb, Vt);
  attn_mfma<<<dim3(NS / 32, KA, NB), 128, 0, stream>>>(qb, Kb, Vt, ob);
  oproj_mfma<<<dim3(4, 280), 256, 0, stream>>>(ob, woat, gates1, bucket_a, counts_a, y_slot);
  ln_gate_kernel<EF, KF, true><<<T / 16, 1024, 0, stream>>>(
      x, y_slot, out, n2g, n2b, gate_m, task, x1b, gates2,
      counts_f, bucket_f, T * KF, accum + 49, accum + 81);
  mlp1_mfma<<<dim3(16, 144), 256, 0, stream>>>(x1b, wit, bi, bucket_f, counts_f, h);
  mlp2_mfma<<<dim3(8, 144), 256, 0, stream>>>(h, womt, bo, gates2, bucket_f, counts_f, y2_slot);
  final_kernel<<<T, 256, 0, stream>>>(y2_slot, out, accum, counts_a, counts_f,
                                      out + (size_t)T * C);
}

// Round 18
// 198.668 us; speedup vs baseline: 1.1557x; 1.1557x over previous
//
#include <hip/hip_runtime.h>
#include <math.h>

namespace {

constexpr int T   = 4096;
constexpr int C   = 512;
constexpr int NB  = 8;
constexpr int NS  = 512;
constexpr int HD  = 64;
constexpr int KA  = 8;
constexpr int EA  = 24;
constexpr int EF  = 16;
constexpr int KF  = 2;
constexpr int HID = 1024;

typedef __attribute__((ext_vector_type(8))) short bf16x8;
typedef __attribute__((ext_vector_type(4))) float f32x4;

__device__ inline unsigned short f2bf(float f) {
  unsigned u = __float_as_uint(f);
  return (unsigned short)((u + 0x7FFFu + ((u >> 16) & 1u)) >> 16);
}
__device__ inline float bf2f(unsigned short u) {
  return __uint_as_float((unsigned)u << 16);
}

template <int E, int TS>
__device__ inline bool tile_from_counts(const int* counts, int tile, int& e_out, int& t0_out) {
  int e = 0;
  for (; e < E; e++) {
    int nt = (counts[e] + TS - 1) / TS;
    if (tile < nt) break;
    tile -= nt;
  }
  e_out = e; t0_out = tile * TS;
  return e < E;
}

// ---- Fused [residual+]LN + gating + bucket-scatter + loss-stats: 16 tokens, 1024 thr ----
template <int E, int K, bool RESID>
__global__ __launch_bounds__(1024) void ln_gate_kernel(
    const float* __restrict__ in, const unsigned short* __restrict__ yslot,
    float* __restrict__ resid_out,
    const float* __restrict__ g, const float* __restrict__ b,
    const float* __restrict__ gate_all, const int* __restrict__ task,
    unsigned short* __restrict__ outb, float* __restrict__ gates,
    int* __restrict__ counts, int* __restrict__ bucket, int stride,
    float* __restrict__ psum_g, float* __restrict__ zsum_g) {
  constexpr int TPB = 16;
  constexpr int XSS = 516;
  int tid = threadIdx.x, lane = tid & 63, wv = tid >> 6;   // 16 waves
  int tb = blockIdx.x * TPB;
  __shared__ float xs[TPB][XSS];
  __shared__ float lp[2][TPB][E];
  __shared__ __align__(16) float Wt[E][XSS];
  __shared__ int idx_s[TPB][8];
  __shared__ float zbuf[TPB];
  __shared__ int lcount[E];
  __shared__ int lbase[E];
  const float* W = gate_all + (size_t)task[0] * C * E;
  for (int i = tid; i < C * E; i += 1024) {
    int c = i / E, e = i - c * E;
    Wt[e][c] = W[i];
  }
  if (tid < E) lcount[tid] = 0;
  int c0 = lane * 8;
  const float4 g0 = *(const float4*)&g[c0], g1 = *(const float4*)&g[c0 + 4];
  const float4 b0 = *(const float4*)&b[c0], b1 = *(const float4*)&b[c0 + 4];
  {
    int tt = wv;
    int t = tb + tt;
    const float* row = in + (size_t)t * C + c0;
    float4 v0 = *(const float4*)&row[0];
    float4 v1 = *(const float4*)&row[4];
    if (RESID) {
      #pragma unroll
      for (int k = 0; k < KA; k++) {
        uint4 u = *(const uint4*)&yslot[((size_t)t * KA + k) * C + c0];
        const unsigned short* us = (const unsigned short*)&u;
        v0.x += bf2f(us[0]); v0.y += bf2f(us[1]); v0.z += bf2f(us[2]); v0.w += bf2f(us[3]);
        v1.x += bf2f(us[4]); v1.y += bf2f(us[5]); v1.z += bf2f(us[6]); v1.w += bf2f(us[7]);
      }
      *(float4*)&resid_out[(size_t)t * C + c0]     = v0;
      *(float4*)&resid_out[(size_t)t * C + c0 + 4] = v1;
    }
    float s = (v0.x + v0.y) + (v0.z + v0.w) + (v1.x + v1.y) + (v1.z + v1.w);
    #pragma unroll
    for (int m = 1; m < 64; m <<= 1) s += __shfl_xor(s, m);
    float mean = s * (1.f / C);
    float d[8] = {v0.x - mean, v0.y - mean, v0.z - mean, v0.w - mean,
                  v1.x - mean, v1.y - mean, v1.z - mean, v1.w - mean};
    float vv = 0.f;
    #pragma unroll
    for (int j = 0; j < 8; j++) vv += d[j] * d[j];
    #pragma unroll
    for (int m = 1; m < 64; m <<= 1) vv += __shfl_xor(vv, m);
    float r = rsqrtf(vv * (1.f / C) + 1e-5f);
    float o[8];
    o[0] = d[0] * r * g0.x + b0.x; o[1] = d[1] * r * g0.y + b0.y;
    o[2] = d[2] * r * g0.z + b0.z; o[3] = d[3] * r * g0.w + b0.w;
    o[4] = d[4] * r * g1.x + b1.x; o[5] = d[5] * r * g1.y + b1.y;
    o[6] = d[6] * r * g1.z + b1.z; o[7] = d[7] * r * g1.w + b1.w;
    *(ushort4*)&outb[(size_t)t * C + c0] =
        make_ushort4(f2bf(o[0]), f2bf(o[1]), f2bf(o[2]), f2bf(o[3]));
    *(ushort4*)&outb[(size_t)t * C + c0 + 4] =
        make_ushort4(f2bf(o[4]), f2bf(o[5]), f2bf(o[6]), f2bf(o[7]));
    #pragma unroll
    for (int j = 0; j < 8; j++) xs[tt][c0 + j] = o[j];
  }
  __syncthreads();
  if (tid < TPB * E * 2) {
    int half = tid / (TPB * E);
    int rem = tid - half * (TPB * E);
    int e = rem % E, tt = rem / E;
    int cb = half * (C / 2);
    float a0 = 0.f, a1 = 0.f, a2 = 0.f, a3 = 0.f;
    float a4 = 0.f, a5 = 0.f, a6 = 0.f, a7 = 0.f;
    #pragma unroll 4
    for (int c = cb; c < cb + C / 2; c += 8) {
      const float4 xv0 = *(const float4*)&xs[tt][c];
      const float4 xv1 = *(const float4*)&xs[tt][c + 4];
      const float4 wv0 = *(const float4*)&Wt[e][c];
      const float4 wv1 = *(const float4*)&Wt[e][c + 4];
      a0 += xv0.x * wv0.x; a1 += xv0.y * wv0.y;
      a2 += xv0.z * wv0.z; a3 += xv0.w * wv0.w;
      a4 += xv1.x * wv1.x; a5 += xv1.y * wv1.y;
      a6 += xv1.z * wv1.z; a7 += xv1.w * wv1.w;
    }
    lp[half][tt][e] = ((a0 + a1) + (a2 + a3)) + ((a4 + a5) + (a6 + a7));
  }
  __syncthreads();
  {
    int tt = wv;
    int t = tb + tt;
    float lgv = (lane < E) ? (lp[0][tt][lane] + lp[1][tt][lane]) : -3.0e38f;
    float mx = lgv;
    #pragma unroll
    for (int m = 1; m < 64; m <<= 1) mx = fmaxf(mx, __shfl_xor(mx, m));
    float pe = (lane < E) ? expf(lgv - mx) : 0.f;
    float sum = pe;
    #pragma unroll
    for (int m = 1; m < 64; m <<= 1) sum += __shfl_xor(sum, m);
    float inv = 1.f / sum;
    float prob = pe * inv;
    if (lane < E) lp[0][tt][lane] = prob;
    if (lane == 0) zbuf[tt] = mx + logf(sum);
    float pv = (lane < E) ? prob : -1.f;
    float gsum = 0.f, myv = 0.f; int myi = 0;
    for (int k = 0; k < K; k++) {
      float bv = pv; int bi_ = lane;
      #pragma unroll
      for (int m = 1; m < 64; m <<= 1) {
        float ov = __shfl_xor(bv, m); int oi = __shfl_xor(bi_, m);
        if (ov > bv || (ov == bv && oi < bi_)) { bv = ov; bi_ = oi; }
      }
      gsum += bv;
      if (lane == k) { myv = bv; myi = bi_; }
      if (lane == bi_) pv = -1.f;
    }
    if (lane < K) {
      float ginv = 1.f / (gsum + 1e-6f);
      gates[(size_t)t * K + lane] = myv * ginv;
      idx_s[tt][lane] = myi;
    }
  }
  __syncthreads();
  if (tid < E) {
    float s = 0.f;
    #pragma unroll
    for (int tt2 = 0; tt2 < TPB; tt2++) s += lp[0][tt2][tid];
    atomicAdd(&psum_g[tid], s);
  }
  if (tid == 64) {
    float z = 0.f;
    #pragma unroll
    for (int tt2 = 0; tt2 < TPB; tt2++) { float l = zbuf[tt2]; z += l * l; }
    atomicAdd(zsum_g, z);
  }
  int my_e = -1, my_lpos = 0;
  if (tid < TPB * K) {
    int tt2 = tid / K, k = tid % K;
    my_e = idx_s[tt2][k];
    my_lpos = atomicAdd(&lcount[my_e], 1);
  }
  __syncthreads();
  if (tid < E) lbase[tid] = lcount[tid] ? atomicAdd(&counts[tid], lcount[tid]) : 0;
  __syncthreads();
  if (my_e >= 0) {
    int tt2 = tid / K, k = tid % K;
    bucket[(size_t)my_e * stride + lbase[my_e] + my_lpos] = (tb + tt2) * K + k;
  }
}

// ---------------- merged transpose+cvt: 64x64 tiles, all 5 weight tensors ----------------
__global__ __launch_bounds__(256) void tcvt_all(
    const float* __restrict__ wq, const float* __restrict__ wo_a,
    const float* __restrict__ wi, const float* __restrict__ wo_m,
    const float* __restrict__ kvw,
    unsigned short* __restrict__ wqt, unsigned short* __restrict__ woat,
    unsigned short* __restrict__ wit, unsigned short* __restrict__ womt,
    unsigned short* __restrict__ kvwt) {
  int bid = blockIdx.x;
  const float* src; unsigned short* dst; int K, N, nx, rem;
  if (bid < 192)       { src = wq;   dst = wqt;  K = 512;  N = 64;   nx = 1;  rem = bid; }
  else if (bid < 384)  { src = wo_a; dst = woat; K = 64;   N = 512;  nx = 8;  rem = bid - 192; }
  else if (bid < 2432) { src = wi;   dst = wit;  K = 512;  N = 1024; nx = 16; rem = bid - 384; }
  else if (bid < 4480) { src = wo_m; dst = womt; K = 1024; N = 512;  nx = 8;  rem = bid - 2432; }
  else                 { src = kvw;  dst = kvwt; K = 512;  N = 128;  nx = 2;  rem = bid - 4480; }
  int per = nx * (K / 64);
  int e = rem / per, r2 = rem % per;
  int kt = (r2 / nx) * 64, nt = (r2 % nx) * 64;
  __shared__ float tile[64][65];
  int tid = threadIdx.x;
  const float* S = src + (size_t)e * K * N;
  for (int i = tid; i < 64 * 16; i += 256) {
    int r = i >> 4, c4 = (i & 15) * 4;
    const float4 v = *(const float4*)&S[(size_t)(kt + r) * N + nt + c4];
    tile[r][c4 + 0] = v.x; tile[r][c4 + 1] = v.y;
    tile[r][c4 + 2] = v.z; tile[r][c4 + 3] = v.w;
  }
  __syncthreads();
  unsigned short* D = dst + (size_t)e * K * N;
  for (int i = tid; i < 64 * 64; i += 256) {
    int k = i & 63, n = i >> 6;
    D[(size_t)(nt + n) * K + kt + k] = f2bf(tile[k][n]);
  }
}

// ---------------- Merged Q GEMM + KV GEMM ----------------
__global__ __launch_bounds__(256) void qkv_mfma(
    const unsigned short* __restrict__ xb, const unsigned short* __restrict__ wqt,
    const unsigned short* __restrict__ kvwt, const float* __restrict__ kvb,
    const int* __restrict__ bucket, const int* __restrict__ counts,
    unsigned short* __restrict__ qb, unsigned short* __restrict__ Kb,
    unsigned short* __restrict__ Vt) {
  __shared__ __align__(16) unsigned short smem[16 * 72 + 128 * 72];
  __shared__ int slots[64];
  __shared__ int se, st0;
  int tid = threadIdx.x;
  int lane = tid & 63, w = tid >> 6;
  int lr = lane & 15, lk = (lane >> 4) * 8, rowq = (lane >> 4) * 4;
  if ((int)blockIdx.y < T / 16) {
    int t0 = blockIdx.y * 16;
    unsigned short* Xs = smem;
    unsigned short* Ws = smem + 16 * 72;
    f32x4 acc[2] = {};
    for (int kc = 0; kc < C; kc += 64) {
      __syncthreads();
      if (tid < 128) {
        int r = tid >> 3, c8 = (tid & 7) * 8;
        *(uint4*)&Xs[r * 72 + c8] = *(const uint4*)&xb[(size_t)(t0 + r) * C + kc + c8];
      }
      #pragma unroll
      for (int it = 0; it < 4; ++it) {
        int i = it * 256 + tid;
        int r = i >> 3, c8 = (i & 7) * 8;
        *(uint4*)&Ws[r * 72 + c8] = *(const uint4*)&kvwt[(size_t)r * C + kc + c8];
      }
      __syncthreads();
      #pragma unroll
      for (int kk = 0; kk < 64; kk += 32) {
        bf16x8 xf = *(const bf16x8*)&Xs[lr * 72 + kk + lk];
        #pragma unroll
        for (int cf = 0; cf < 2; cf++) {
          bf16x8 wf = *(const bf16x8*)&Ws[(w * 32 + cf * 16 + lr) * 72 + kk + lk];
          acc[cf] = __builtin_amdgcn_mfma_f32_16x16x32_bf16(wf, xf, acc[cf], 0, 0, 0);
        }
      }
    }
    int t = t0 + lr;
    int bb = t >> 9, n = t & (NS - 1);
    #pragma unroll
    for (int cf = 0; cf < 2; cf++) {
      #pragma unroll
      for (int r2 = 0; r2 < 4; r2++) {
        int c = w * 32 + cf * 16 + rowq + r2;
        float v = acc[cf][r2] + kvb[c];
        if (c < HD) Kb[(size_t)t * HD + c] = f2bf(v);
        else        Vt[((size_t)bb * HD + (c - HD)) * NS + n] = f2bf(v);
      }
    }
  } else {
    if (tid == 0) {
      int e, t0;
      bool ok = tile_from_counts<EA, 64>(counts, blockIdx.y - T / 16, e, t0);
      se = ok ? e : -1; st0 = t0;
    }
    __syncthreads();
    if (se < 0) return;
    int e = se, t0 = st0;
    int cnt = counts[e];
    unsigned short* Xb = smem;
    unsigned short* Wb = smem + 64 * 72;
    if (tid < 64) {
      int ii = t0 + tid;
      slots[tid] = (ii < cnt) ? bucket[(size_t)e * (T * KA) + ii] : -1;
    }
    __syncthreads();
    f32x4 acc[4] = {};
    for (int kc = 0; kc < C; kc += 64) {
      __syncthreads();
      #pragma unroll
      for (int it = 0; it < 2; ++it) {
        int i = it * 256 + tid;
        int r = i >> 3, c8 = (i & 7) * 8;
        int s = slots[r];
        uint4 v = make_uint4(0u, 0u, 0u, 0u);
        if (s >= 0) v = *(const uint4*)&xb[(size_t)(s >> 3) * C + kc + c8];
        *(uint4*)&Xb[r * 72 + c8] = v;
      }
      #pragma unroll
      for (int it = 0; it < 2; ++it) {
        int i = it * 256 + tid;
        int r = i >> 3, c8 = (i & 7) * 8;
        *(uint4*)&Wb[r * 72 + c8] = *(const uint4*)&wqt[((size_t)e * HD + r) * C + kc + c8];
      }
      __syncthreads();
      #pragma unroll
      for (int kk = 0; kk < 64; kk += 32) {
        bf16x8 a = *(const bf16x8*)&Wb[(w * 16 + lr) * 72 + kk + lk];
        #pragma unroll
        for (int mf = 0; mf < 4; mf++) {
          bf16x8 b = *(const bf16x8*)&Xb[(mf * 16 + lr) * 72 + kk + lk];
          acc[mf] = __builtin_amdgcn_mfma_f32_16x16x32_bf16(a, b, acc[mf], 0, 0, 0);
        }
      }
    }
    #pragma unroll
    for (int mf = 0; mf < 4; mf++) {
      int s = slots[mf * 16 + lr];
      if (s < 0) continue;
      ushort4 v = make_ushort4(f2bf(0.125f * acc[mf][0]), f2bf(0.125f * acc[mf][1]),
                               f2bf(0.125f * acc[mf][2]), f2bf(0.125f * acc[mf][3]));
      *(ushort4*)&qb[(size_t)s * HD + w * 16 + rowq] = v;
    }
  }
}

// ---------------- MFMA flash attention: 32-row q-tiles, 128 threads (lockstep staging) ----------------
__global__ __launch_bounds__(128) void attn_mfma(
    const unsigned short* __restrict__ qb, const unsigned short* __restrict__ Kb,
    const unsigned short* __restrict__ Vt, unsigned short* __restrict__ ob) {
  int qt = blockIdx.x, h = blockIdx.y, b = blockIdx.z;
  int tid = threadIdx.x;
  __shared__ __align__(16) unsigned short Qs[32][72];
  __shared__ __align__(16) unsigned short Ks[64][72];
  __shared__ __align__(16) unsigned short Vs[64][72];
  __shared__ __align__(16) unsigned short Ps[32][72];
  int i0 = qt * 32;
  #pragma unroll
  for (int it = 0; it < 2; ++it) {
    int i = it * 128 + tid;
    int r = i >> 3, c8 = (i & 7) * 8;
    *(uint4*)&Qs[r][c8] = *(const uint4*)&qb[(((size_t)(b * NS + i0 + r)) * KA + h) * HD + c8];
  }
  int lane = tid & 63, w = tid >> 6;   // 2 waves
  int lr = lane & 15, lk = (lane >> 4) * 8, rowq = (lane >> 4) * 4;
  f32x4 acc_o[4] = {};
  float m_run = -3.0e38f, l_run = 0.f;
  for (int jt = 0; jt < NS / 64; ++jt) {
    __syncthreads();
    #pragma unroll
    for (int it = 0; it < 4; ++it) {
      int i = it * 128 + tid;
      int r = i >> 3, c8 = (i & 7) * 8;
      *(uint4*)&Ks[r][c8] = *(const uint4*)&Kb[((size_t)(b * NS + jt * 64 + r)) * HD + c8];
      *(uint4*)&Vs[r][c8] = *(const uint4*)&Vt[((size_t)b * HD + r) * NS + jt * 64 + c8];
    }
    __syncthreads();
    f32x4 acc_s[4] = {};
    #pragma unroll
    for (int kk = 0; kk < 64; kk += 32) {
      bf16x8 qf = *(const bf16x8*)&Qs[w * 16 + lr][kk + lk];
      #pragma unroll
      for (int kf = 0; kf < 4; kf++) {
        bf16x8 kr = *(const bf16x8*)&Ks[kf * 16 + lr][kk + lk];
        acc_s[kf] = __builtin_amdgcn_mfma_f32_16x16x32_bf16(kr, qf, acc_s[kf], 0, 0, 0);
      }
    }
    float pmax = acc_s[0][0];
    #pragma unroll
    for (int kf = 0; kf < 4; kf++)
      #pragma unroll
      for (int r = 0; r < 4; r++) pmax = fmaxf(pmax, acc_s[kf][r]);
    pmax = fmaxf(pmax, __shfl_xor(pmax, 16));
    pmax = fmaxf(pmax, __shfl_xor(pmax, 32));
    float m_new = fmaxf(m_run, pmax);
    float scl = expf(m_run - m_new);
    float rs = 0.f;
    #pragma unroll
    for (int kf = 0; kf < 4; kf++)
      #pragma unroll
      for (int r = 0; r < 4; r++) {
        float pv = expf(acc_s[kf][r] - m_new);
        rs += pv;
        Ps[w * 16 + lr][kf * 16 + rowq + r] = f2bf(pv);
      }
    rs += __shfl_xor(rs, 16);
    rs += __shfl_xor(rs, 32);
    l_run = l_run * scl + rs;
    m_run = m_new;
    __syncthreads();
    #pragma unroll
    for (int df = 0; df < 4; df++) {
      acc_o[df][0] *= scl; acc_o[df][1] *= scl;
      acc_o[df][2] *= scl; acc_o[df][3] *= scl;
    }
    #pragma unroll
    for (int kk = 0; kk < 64; kk += 32) {
      bf16x8 pf = *(const bf16x8*)&Ps[w * 16 + lr][kk + lk];
      #pragma unroll
      for (int df = 0; df < 4; df++) {
        bf16x8 vf = *(const bf16x8*)&Vs[df * 16 + lr][kk + lk];
        acc_o[df] = __builtin_amdgcn_mfma_f32_16x16x32_bf16(vf, pf, acc_o[df], 0, 0, 0);
      }
    }
  }
  float inv = 1.f / l_run;
  int token = b * NS + i0 + w * 16 + lr;
  #pragma unroll
  for (int df = 0; df < 4; df++) {
    ushort4 v = make_ushort4(f2bf(acc_o[df][0] * inv), f2bf(acc_o[df][1] * inv),
                             f2bf(acc_o[df][2] * inv), f2bf(acc_o[df][3] * inv));
    *(ushort4*)&ob[((size_t)token * KA + h) * HD + df * 16 + rowq] = v;
  }
}

// ---------------- MFMA output proj: 128 slots x 128 cols, K=64 ----------------
__global__ __launch_bounds__(256) void oproj_mfma(
    const unsigned short* __restrict__ ob, const unsigned short* __restrict__ wot,
    const float* __restrict__ gates, const int* __restrict__ bucket,
    const int* __restrict__ counts, unsigned short* __restrict__ y_slot) {
  __shared__ int se, st0;
  int tid = threadIdx.x;
  if (tid == 0) {
    int e, t0;
    bool ok = tile_from_counts<EA, 128>(counts, blockIdx.y, e, t0);
    se = ok ? e : -1; st0 = t0;
  }
  __syncthreads();
  if (se < 0) return;
  int e = se, t0 = st0;
  int c0 = blockIdx.x * 128;
  int cnt = counts[e];
  __shared__ int slots[128];
  __shared__ float gs[128];
  __shared__ __align__(16) unsigned short Xb[128][72];
  __shared__ __align__(16) unsigned short Wb[128][72];
  if (tid < 128) {
    int ii = t0 + tid;
    int s = (ii < cnt) ? bucket[(size_t)e * (T * KA) + ii] : -1;
    slots[tid] = s;
    gs[tid] = (s >= 0) ? gates[s] : 0.f;
  }
  __syncthreads();
  #pragma unroll
  for (int it = 0; it < 4; ++it) {
    int i = it * 256 + tid;
    int r = i >> 3, c8 = (i & 7) * 8;
    int s = slots[r];
    uint4 vo = make_uint4(0u, 0u, 0u, 0u);
    if (s >= 0) {
      float g = gs[r];
      uint4 u = *(const uint4*)&ob[(size_t)s * HD + c8];
      const unsigned short* us = (const unsigned short*)&u;
      unsigned short* vs = (unsigned short*)&vo;
      #pragma unroll
      for (int k = 0; k < 8; k++) vs[k] = f2bf(g * bf2f(us[k]));
    }
    *(uint4*)&Xb[r][c8] = vo;
  }
  #pragma unroll
  for (int it = 0; it < 4; ++it) {
    int i = it * 256 + tid;
    int r = i >> 3, c8 = (i & 7) * 8;
    *(uint4*)&Wb[r][c8] = *(const uint4*)&wot[((size_t)e * C + c0 + r) * HD + c8];
  }
  __syncthreads();
  int lane = tid & 63, wid = tid >> 6;
  int wr = wid & 1, wc = wid >> 1;
  int lr = lane & 15, lk = (lane >> 4) * 8, rowq = (lane >> 4) * 4;
  f32x4 acc[4][4] = {};
  #pragma unroll
  for (int kk = 0; kk < 64; kk += 32) {
    bf16x8 a[4], b[4];
    #pragma unroll
    for (int nf = 0; nf < 4; nf++) a[nf] = *(const bf16x8*)&Wb[wc * 64 + nf * 16 + lr][kk + lk];
    #pragma unroll
    for (int mf = 0; mf < 4; mf++) b[mf] = *(const bf16x8*)&Xb[wr * 64 + mf * 16 + lr][kk + lk];
    #pragma unroll
    for (int nf = 0; nf < 4; nf++)
      #pragma unroll
      for (int mf = 0; mf < 4; mf++)
        acc[nf][mf] = __builtin_amdgcn_mfma_f32_16x16x32_bf16(a[nf], b[mf], acc[nf][mf], 0, 0, 0);
  }
  #pragma unroll
  for (int mf = 0; mf < 4; mf++) {
    int si = wr * 64 + mf * 16 + lr;
    int s = slots[si];
    if (s < 0) continue;
    size_t base = (size_t)s * C + c0 + wc * 64;
    #pragma unroll
    for (int nf = 0; nf < 4; nf++) {
      ushort4 v = make_ushort4(f2bf(acc[nf][mf][0]), f2bf(acc[nf][mf][1]),
                               f2bf(acc[nf][mf][2]), f2bf(acc[nf][mf][3]));
      *(ushort4*)&y_slot[base + nf * 16 + rowq] = v;
    }
  }
}

// ---------------- MFMA MLP1: 64 slots x 64 cols, gelu epilogue ----------------
__global__ __launch_bounds__(256) void mlp1_mfma(
    const unsigned short* __restrict__ xb, const unsigned short* __restrict__ wit,
    const float* __restrict__ bi, const int* __restrict__ bucket,
    const int* __restrict__ counts, unsigned short* __restrict__ h) {
  __shared__ int se, st0;
  int tid = threadIdx.x;
  if (tid == 0) {
    int e, t0;
    bool ok = tile_from_counts<EF, 64>(counts, blockIdx.y, e, t0);
    se = ok ? e : -1; st0 = t0;
  }
  __syncthreads();
  if (se < 0) return;
  int e = se, t0 = st0;
  int j0 = blockIdx.x * 64;
  int cnt = counts[e];
  __shared__ int slots[64];
  __shared__ __align__(16) unsigned short Xb[64][72];
  __shared__ __align__(16) unsigned short Wb[64][72];
  if (tid < 64) {
    int ii = t0 + tid;
    slots[tid] = (ii < cnt) ? bucket[(size_t)e * (T * KF) + ii] : -1;
  }
  __syncthreads();
  int lane = tid & 63, w = tid >> 6;
  int lr = lane & 15, lk = (lane >> 4) * 8, rowq = (lane >> 4) * 4;
  f32x4 acc[4] = {};
  for (int kc = 0; kc < C; kc += 64) {
    __syncthreads();
    #pragma unroll
    for (int it = 0; it < 2; ++it) {
      int i = it * 256 + tid;
      int r = i >> 3, c8 = (i & 7) * 8;
      int s = slots[r];
      uint4 v = make_uint4(0u, 0u, 0u, 0u);
      if (s >= 0) v = *(const uint4*)&xb[(size_t)(s >> 1) * C + kc + c8];
      *(uint4*)&Xb[r][c8] = v;
    }
    #pragma unroll
    for (int it = 0; it < 2; ++it) {
      int i = it * 256 + tid;
      int r = i >> 3, c8 = (i & 7) * 8;
      *(uint4*)&Wb[r][c8] = *(const uint4*)&wit[((size_t)e * HID + j0 + r) * C + kc + c8];
    }
    __syncthreads();
    #pragma unroll
    for (int kk = 0; kk < 64; kk += 32) {
      bf16x8 a = *(const bf16x8*)&Wb[w * 16 + lr][kk + lk];
      #pragma unroll
      for (int mf = 0; mf < 4; mf++) {
        bf16x8 b = *(const bf16x8*)&Xb[mf * 16 + lr][kk + lk];
        acc[mf] = __builtin_amdgcn_mfma_f32_16x16x32_bf16(a, b, acc[mf], 0, 0, 0);
      }
    }
  }
  #pragma unroll
  for (int mf = 0; mf < 4; mf++) {
    int s = slots[mf * 16 + lr];
    if (s < 0) continue;
    int j = j0 + w * 16 + rowq;
    const float4 b4 = *(const float4*)&bi[(size_t)e * HID + j];
    float v0 = acc[mf][0] + b4.x, v1 = acc[mf][1] + b4.y;
    float v2 = acc[mf][2] + b4.z, v3 = acc[mf][3] + b4.w;
    v0 = 0.5f * v0 * (1.f + erff(v0 * 0.70710678118654752f));
    v1 = 0.5f * v1 * (1.f + erff(v1 * 0.70710678118654752f));
    v2 = 0.5f * v2 * (1.f + erff(v2 * 0.70710678118654752f));
    v3 = 0.5f * v3 * (1.f + erff(v3 * 0.70710678118654752f));
    *(ushort4*)&h[(size_t)s * HID + j] = make_ushort4(f2bf(v0), f2bf(v1), f2bf(v2), f2bf(v3));
  }
}

// ---------------- MFMA MLP2: 64 slots x 64 cols, gate+bias epilogue ----------------
__global__ __launch_bounds__(256) void mlp2_mfma(
    const unsigned short* __restrict__ h, const unsigned short* __restrict__ wot,
    const float* __restrict__ bo, const float* __restrict__ gates2,
    const int* __restrict__ bucket, const int* __restrict__ counts,
    unsigned short* __restrict__ y2) {
  __shared__ int se, st0;
  int tid = threadIdx.x;
  if (tid == 0) {
    int e, t0;
    bool ok = tile_from_counts<EF, 64>(counts, blockIdx.y, e, t0);
    se = ok ? e : -1; st0 = t0;
  }
  __syncthreads();
  if (se < 0) return;
  int e = se, t0 = st0;
  int c0 = blockIdx.x * 64;
  int cnt = counts[e];
  __shared__ int slots[64];
  __shared__ __align__(16) unsigned short Xb[64][72];
  __shared__ __align__(16) unsigned short Wb[64][72];
  if (tid < 64) {
    int ii = t0 + tid;
    slots[tid] = (ii < cnt) ? bucket[(size_t)e * (T * KF) + ii] : -1;
  }
  __syncthreads();
  int lane = tid & 63, w = tid >> 6;
  int lr = lane & 15, lk = (lane >> 4) * 8, rowq = (lane >> 4) * 4;
  f32x4 acc[4] = {};
  for (int kc = 0; kc < HID; kc += 64) {
    __syncthreads();
    #pragma unroll
    for (int it = 0; it < 2; ++it) {
      int i = it * 256 + tid;
      int r = i >> 3, c8 = (i & 7) * 8;
      int s = slots[r];
      uint4 v = make_uint4(0u, 0u, 0u, 0u);
      if (s >= 0) v = *(const uint4*)&h[(size_t)s * HID + kc + c8];
      *(uint4*)&Xb[r][c8] = v;
    }
    #pragma unroll
    for (int it = 0; it < 2; ++it) {
      int i = it * 256 + tid;
      int r = i >> 3, c8 = (i & 7) * 8;
      *(uint4*)&Wb[r][c8] = *(const uint4*)&wot[((size_t)e * C + c0 + r) * HID + kc + c8];
    }
    __syncthreads();
    #pragma unroll
    for (int kk = 0; kk < 64; kk += 32) {
      bf16x8 a = *(const bf16x8*)&Wb[w * 16 + lr][kk + lk];
      #pragma unroll
      for (int mf = 0; mf < 4; mf++) {
        bf16x8 b = *(const bf16x8*)&Xb[mf * 16 + lr][kk + lk];
        acc[mf] = __builtin_amdgcn_mfma_f32_16x16x32_bf16(a, b, acc[mf], 0, 0, 0);
      }
    }
  }
  #pragma unroll
  for (int mf = 0; mf < 4; mf++) {
    int s = slots[mf * 16 + lr];
    if (s < 0) continue;
    float g = gates2[s];
    int cc = c0 + w * 16 + rowq;
    const float4 b4 = *(const float4*)&bo[(size_t)e * C + cc];
    ushort4 v = make_ushort4(f2bf(g * (acc[mf][0] + b4.x)),
                             f2bf(g * (acc[mf][1] + b4.y)),
                             f2bf(g * (acc[mf][2] + b4.z)),
                             f2bf(g * (acc[mf][3] + b4.w)));
    *(ushort4*)&y2[(size_t)s * C + cc] = v;
  }
}

// ---------------- Final residual add (bf16 slots) + scalar loss (block 0) ----------------
__global__ void final_kernel(const unsigned short* __restrict__ y2, float* __restrict__ xout,
                             const float* __restrict__ acc, const int* __restrict__ ca,
                             const int* __restrict__ cf, float* __restrict__ loss_out) {
  int t = blockIdx.x, tid = threadIdx.x;
  int c = tid * 2;
  unsigned u0 = *(const unsigned*)&y2[(size_t)(t * 2) * C + c];
  unsigned u1 = *(const unsigned*)&y2[(size_t)(t * 2 + 1) * C + c];
  xout[(size_t)t * C + c]     += bf2f((unsigned short)(u0 & 0xFFFF)) + bf2f((unsigned short)(u1 & 0xFFFF));
  xout[(size_t)t * C + c + 1] += bf2f((unsigned short)(u0 >> 16)) + bf2f((unsigned short)(u1 >> 16));
  if (t == 0 && tid == 0) {
    const float* p1 = acc;      float z1 = acc[48];
    const float* p2 = acc + 49; float z2 = acc[81];
    float sp1 = 0.f, sf1 = 0.f;
    for (int e = 0; e < 24; e++) { sp1 += p1[e]; sf1 += (float)ca[e]; }
    float sw1 = 0.f;
    for (int e = 0; e < 24; e++) sw1 += (p1[e] / sp1) * ((float)ca[e] / sf1);
    sw1 *= 24.f;
    float sp2 = 0.f, sf2 = 0.f;
    for (int e = 0; e < 16; e++) { sp2 += p2[e]; sf2 += (float)cf[e]; }
    float sw2 = 0.f;
    for (int e = 0; e < 16; e++) sw2 += (p2[e] / sp2) * ((float)cf[e] / sf2);
    sw2 *= 16.f;
    loss_out[0] = 0.01f * sw1 + 0.001f * (z1 / T) + 0.01f * sw2 + 0.001f * (z2 / T);
  }
}

}  // namespace

extern "C" void kernel_launch(void* const* d_in, const int* in_sizes, int n_in,
                              void* d_out, int out_size, void* d_ws, size_t ws_size,
                              hipStream_t stream) {
  const float* x      = (const float*)d_in[0];
  const int*   task   = (const int*)d_in[1];
  const float* n1g    = (const float*)d_in[2];
  const float* n1b    = (const float*)d_in[3];
  const float* gate_a = (const float*)d_in[4];
  const float* wq     = (const float*)d_in[5];
  const float* wo_a   = (const float*)d_in[6];
  const float* kvw    = (const float*)d_in[7];
  const float* kvb    = (const float*)d_in[8];
  const float* n2g    = (const float*)d_in[9];
  const float* n2b    = (const float*)d_in[10];
  const float* gate_m = (const float*)d_in[11];
  const float* wi     = (const float*)d_in[12];
  const float* bi     = (const float*)d_in[13];
  const float* wo_m   = (const float*)d_in[14];
  const float* bo     = (const float*)d_in[15];
  float* out = (float*)d_out;

  char* p = (char*)d_ws;
  unsigned short* x1b = (unsigned short*)p; p += (size_t)T * C * 2;
  unsigned short* qb = (unsigned short*)p;  p += (size_t)T * KA * HD * 2;
  unsigned short* ob = (unsigned short*)p;  p += (size_t)T * KA * HD * 2;
  unsigned short* Kb = (unsigned short*)p;  p += (size_t)T * HD * 2;
  unsigned short* Vt = (unsigned short*)p;  p += (size_t)T * HD * 2;
  char* un = p;                      p += (size_t)T * KA * C * 2;
  unsigned short* y_slot  = (unsigned short*)un;
  unsigned short* h       = (unsigned short*)un;
  unsigned short* y2_slot = (unsigned short*)(un + (size_t)T * KF * HID * 2);
  unsigned short* wqt = (unsigned short*)p;  p += (size_t)EA * C * HD * 2;
  unsigned short* woat = (unsigned short*)p; p += (size_t)EA * HD * C * 2;
  unsigned short* wit = (unsigned short*)p;  p += (size_t)EF * C * HID * 2;
  unsigned short* womt = (unsigned short*)p; p += (size_t)EF * HID * C * 2;
  unsigned short* kvwt = (unsigned short*)p; p += (size_t)(2 * HD) * C * 2;
  float* gates1 = (float*)p;         p += (size_t)T * KA * 4;
  float* gates2 = (float*)p;         p += (size_t)T * KF * 4;
  int* bucket_a = (int*)p;           p += (size_t)EA * (T * KA) * 4;
  int* bucket_f = (int*)p;           p += (size_t)EF * (T * KF) * 4;
  int* counts_a = (int*)p;           p += 32 * 4;
  int* counts_f = (int*)p;           p += 32 * 4;
  float* accum = (float*)p;          p += 128 * 4;

  hipMemsetAsync(counts_a, 0, (32 + 32 + 128) * 4, stream);

  tcvt_all<<<4496, 256, 0, stream>>>(wq, wo_a, wi, wo_m, kvw, wqt, woat, wit, womt, kvwt);

  ln_gate_kernel<EA, KA, false><<<T / 16, 1024, 0, stream>>>(
      x, y_slot, out, n1g, n1b, gate_a, task, x1b, gates1,
      counts_a, bucket_a, T * KA, accum, accum + 48);
  qkv_mfma<<<dim3(1, T / 16 + 536), 256, 0, stream>>>(x1b, wqt, kvwt, kvb,
                                                      bucket_a, counts_a, qb, Kb, Vt);
  attn_mfma<<<dim3(NS / 32, KA, NB), 128, 0, stream>>>(qb, Kb, Vt, ob);
  oproj_mfma<<<dim3(4, 280), 256, 0, stream>>>(ob, woat, gates1, bucket_a, counts_a, y_slot);
  ln_gate_kernel<EF, KF, true><<<T / 16, 1024, 0, stream>>>(
      x, y_slot, out, n2g, n2b, gate_m, task, x1b, gates2,
      counts_f, bucket_f, T * KF, accum + 49, accum + 81);
  mlp1_mfma<<<dim3(16, 144), 256, 0, stream>>>(x1b, wit, bi, bucket_f, counts_f, h);
  mlp2_mfma<<<dim3(8, 144), 256, 0, stream>>>(h, womt, bo, gates2, bucket_f, counts_f, y2_slot);
  final_kernel<<<T, 256, 0, stream>>>(y2_slot, out, accum, counts_a, counts_f,
                                      out + (size_t)T * C);
}